// Round 10
// baseline (4053.014 us; speedup 1.0000x reference)
//
#include <hip/hip_runtime.h>
#include <hip/hip_bf16.h>
#include <cstdint>
#include <cstddef>

#define B_ 2
#define N_ 2048
#define F_ 1024
#define H_ 16
#define D_ 64
#define LOG2E 1.44269504f

typedef float f32x4 __attribute__((ext_vector_type(4)));
typedef short s16x8 __attribute__((ext_vector_type(8)));
typedef short s16x4 __attribute__((ext_vector_type(4)));

__device__ __forceinline__ unsigned short f2bf(float f) {
  union { __hip_bfloat16 h; unsigned short u; } c;
  c.h = __float2bfloat16(f);
  return c.u;
}

// hardware 2^x (v_exp_f32 IS base-2). plain exp2f lowers to the precise
// __ocml_exp2_f32 libm path (round-8 lesson: VALUBusy 31.6->38.4).
__device__ __forceinline__ float exp2_hw(float x) {
  float r;
  asm("v_exp_f32 %0, %1" : "=v"(r) : "v"(x));
  return r;
}

// raw barrier: drain LDS ops only; global loads stay in flight (T3/T4).
__device__ __forceinline__ void bar_lgkm() {
  asm volatile("s_waitcnt lgkmcnt(0)" ::: "memory");
  __builtin_amdgcn_s_barrier();
}

// async global->LDS, 16B per lane; LDS dest = uniform base + lane*16.
__device__ __forceinline__ void gload_lds16(const void* g, void* l) {
  __builtin_amdgcn_global_load_lds(
      (const __attribute__((address_space(1))) void*)g,
      (__attribute__((address_space(3))) void*)l, 16, 0, 0);
}

// ---------------------------------------------------------------------
// fp32 -> bf16 bulk convert (8 elems/thread)
// ---------------------------------------------------------------------
__global__ __launch_bounds__(256) void cvt_bf16(const float* __restrict__ in,
                                                unsigned short* __restrict__ out,
                                                int n8) {
  const int t = blockIdx.x * 256 + threadIdx.x;
  if (t >= n8) return;
  const float4* p = (const float4*)in + (size_t)t * 2;
  float4 a = p[0], b = p[1];
  s16x8 o;
  o[0] = f2bf(a.x); o[1] = f2bf(a.y); o[2] = f2bf(a.z); o[3] = f2bf(a.w);
  o[4] = f2bf(b.x); o[5] = f2bf(b.y); o[6] = f2bf(b.z); o[7] = f2bf(b.w);
  *((s16x8*)out + t) = o;
}

// ---------------------------------------------------------------------
// w_qkv fp32 -> bf16 with row permutation: out row colp = c*1024 + h*64 + d
// ---------------------------------------------------------------------
__global__ __launch_bounds__(256) void cvt_wqkv_perm(const float* __restrict__ in,
                                                     unsigned short* __restrict__ out) {
  const int t = blockIdx.x * 256 + threadIdx.x;
  const int rowp = t >> 7;
  const int kk = (t & 127) * 8;
  const int c = rowp >> 10, rem = rowp & 1023;
  const int h = rem >> 6, d = rem & 63;
  const float* p = in + (size_t)(h * 192 + d * 3 + c) * 1024 + kk;
  float4 a = *(const float4*)p, b = *(const float4*)(p + 4);
  s16x8 o;
  o[0] = f2bf(a.x); o[1] = f2bf(a.y); o[2] = f2bf(a.z); o[3] = f2bf(a.w);
  o[4] = f2bf(b.x); o[5] = f2bf(b.y); o[6] = f2bf(b.z); o[7] = f2bf(b.w);
  *((s16x8*)&out[(size_t)rowp * 1024 + kk]) = o;
}

// ---------------------------------------------------------------------
// sum the four j-quarter fp32 O partials -> bf16 O1
// ---------------------------------------------------------------------
__global__ __launch_bounds__(256) void cvt_sum4(const float* __restrict__ a,
                                                unsigned short* __restrict__ out) {
  const int t = blockIdx.x * 256 + threadIdx.x;
  const size_t stride = (size_t)B_ * N_ * 1024 / 4;  // in float4 units
  float4 x0 = *((const float4*)a + t);
  float4 x1 = *((const float4*)a + stride + t);
  float4 x2 = *((const float4*)a + 2 * stride + t);
  float4 x3 = *((const float4*)a + 3 * stride + t);
  s16x4 o;
  o[0] = f2bf((x0.x + x1.x) + (x2.x + x3.x));
  o[1] = f2bf((x0.y + x1.y) + (x2.y + x3.y));
  o[2] = f2bf((x0.z + x1.z) + (x2.z + x3.z));
  o[3] = f2bf((x0.w + x1.w) + (x2.w + x3.w));
  *((s16x4*)out + t) = o;
}

// ---------------------------------------------------------------------
// MFMA GEMM: global_load_lds width=16 staging into a LINEAR [128][64]
// LDS tile + XOR slot-swizzle (both-sides-or-neither, rule #21):
//   - dest is linear (async op writes base+lane*16), so the SOURCE is
//     permuted: lane l (row r = c*8 + l>>3, dest slot l&7) loads global
//     16B-slot (l&7)^(l>>3) of its row.
//   - reads apply the same XOR: slot' = (ks*4+lq) ^ (R&7).
// ---------------------------------------------------------------------
template <int MODE>
__global__ __launch_bounds__(256) void gemm_bf16(const unsigned short* __restrict__ A,
                                                 const unsigned short* __restrict__ W,
                                                 float* __restrict__ o0,
                                                 unsigned short* __restrict__ oQ,
                                                 unsigned short* __restrict__ oK,
                                                 unsigned short* __restrict__ oVt) {
  __shared__ unsigned short As[128 * 64];
  __shared__ unsigned short Bs[128 * 64];
  const int m0 = blockIdx.y * 128, c0 = blockIdx.x * 128;
  const int tid = threadIdx.x;
  const int wave = tid >> 6, lane = tid & 63;
  const int wm = (wave & 1) * 64, wn = (wave >> 1) * 64;
  const int lm = lane & 15, lq = lane >> 4;
  const int srow = lane >> 3;                 // row within 8-row chunk
  const int skq = ((lane & 7) ^ srow) * 8;    // SWIZZLED source slot (shorts)
  const int lm7 = lm & 7;
  f32x4 acc[4][4] = {};
  for (int k0 = 0; k0 < 1024; k0 += 64) {
#pragma unroll
    for (int it = 0; it < 4; ++it) {
      const int c = wave * 4 + it;     // chunk: 8 rows x 64 shorts = 1 KB
      const int row = c * 8 + srow;
      gload_lds16(&A[(size_t)(m0 + row) * 1024 + k0 + skq], &As[c * 512]);
      gload_lds16(&W[(size_t)(c0 + row) * 1024 + k0 + skq], &Bs[c * 512]);
    }
    __syncthreads();  // drains vmcnt (async LDS deposits complete)
#pragma unroll
    for (int ks = 0; ks < 2; ++ks) {
      s16x8 af[4], bfr[4];
#pragma unroll
      for (int i = 0; i < 4; ++i) {
        const int Ra = wm + i * 16 + lm;
        const int Rb = wn + i * 16 + lm;
        af[i] = *(const s16x8*)&As[Ra * 64 + (((ks * 4 + lq) ^ lm7) * 8)];
        bfr[i] = *(const s16x8*)&Bs[Rb * 64 + (((ks * 4 + lq) ^ lm7) * 8)];
      }
#pragma unroll
      for (int i = 0; i < 4; ++i)
#pragma unroll
        for (int j = 0; j < 4; ++j)
          acc[i][j] = __builtin_amdgcn_mfma_f32_16x16x32_bf16(af[i], bfr[j], acc[i][j], 0, 0, 0);
    }
    __syncthreads();
  }
  if (MODE == 1) {
#pragma unroll
    for (int i = 0; i < 4; ++i)
#pragma unroll
      for (int j = 0; j < 4; ++j)
#pragma unroll
        for (int r = 0; r < 4; ++r) {
          const int m = m0 + wm + i * 16 + lq * 4 + r;
          const int col = c0 + wn + j * 16 + lm;
          o0[(size_t)m * 1024 + col] = acc[i][j][r];
        }
  } else {
    const int cls = blockIdx.x >> 3;
    const int colbase = (blockIdx.x & 7) * 128;
    if (cls == 0) {
#pragma unroll
      for (int i = 0; i < 4; ++i)
#pragma unroll
        for (int j = 0; j < 4; ++j) {
          const int cl = colbase + wn + j * 16 + lm;
          const int h = cl >> 6, d = cl & 63;
#pragma unroll
          for (int r = 0; r < 4; ++r) {
            const int m = m0 + wm + i * 16 + lq * 4 + r;
            const int bb = m >> 11, n = m & 2047;
            oQ[(((size_t)bb * H_ + h) * N_ + n) * D_ + d] = f2bf(acc[i][j][r]);
          }
        }
    } else if (cls == 1) {
#pragma unroll
      for (int i = 0; i < 4; ++i)
#pragma unroll
        for (int j = 0; j < 4; ++j) {
          const int cl = colbase + wn + j * 16 + lm;
          const int h = cl >> 6, d = cl & 63;
#pragma unroll
          for (int r = 0; r < 4; ++r) {
            const int m = m0 + wm + i * 16 + lq * 4 + r;
            const int bb = m >> 11, n = m & 2047;
            const size_t idx = (((size_t)bb * H_ + h) * N_ + n) * D_ + d;
            o0[idx] = acc[i][j][r];
            oK[idx] = f2bf(acc[i][j][r]);
          }
        }
    } else {
#pragma unroll
      for (int i = 0; i < 4; ++i) {
        const int n0 = m0 + wm + i * 16 + lq * 4;
        const int bb = n0 >> 11, nl = n0 & 2047;
#pragma unroll
        for (int j = 0; j < 4; ++j) {
          const int cl = colbase + wn + j * 16 + lm;
          const int h = cl >> 6, d = cl & 63;
          s16x4 vp;
#pragma unroll
          for (int r = 0; r < 4; ++r) {
            const size_t idx = (((size_t)bb * H_ + h) * N_ + nl + r) * D_ + d;
            o0[(size_t)B_ * H_ * N_ * D_ + idx] = acc[i][j][r];
            vp[r] = (short)f2bf(acc[i][j][r]);
          }
          *(s16x4*)&oVt[(((size_t)bb * H_ + h) * D_ + d) * N_ + nl] = vp;
        }
      }
    }
  }
}

// =====================================================================
// Fused attention v14 = v13 structure + region ILP reorder:
//   - 8 S-fragment ds_reads hoisted ABOVE the scores[t+1] MFMA cluster
//     (LDS latency hides under register-only MFMAs, not the premix
//     chain).
//   - vt double-buffered in registers (vtbuf[2][4], parity-static under
//     unroll 2): next V load ISSUES before the AV MFMAs consume the
//     current set (HBM latency hides under 8 MFMAs).
//   - AV ap ds_reads first, then V loads, then MFMAs.
//   All waves run identical code (no round-7 divergence), all array
//   indices compile-time (rule #20). Regs ~90 arch + 32 acc <= 128.
// =====================================================================
#define SS_J 20
#define SLOT 320
#define SS_I 644                  // 2*SLOT + 4 pad
#define SS_HALF (32 * SS_I + 16)  // one S buffer (+16 tail pad), shorts
#define PS_J 36
#define PS_G 1156                 // 32*36 + 4
#define PS_HALF (16 * PS_G)       // one P buffer, shorts

__device__ __forceinline__ f32x4 mfma16(s16x8 a, s16x8 b, f32x4 c) {
  return __builtin_amdgcn_mfma_f32_16x16x32_bf16(a, b, c, 0, 0, 0);
}

// single-head K fragment load: kr[jt][half]
__device__ __forceinline__ void load_k1(s16x8 (&kr)[2][2],
                                        const unsigned short* __restrict__ Kb,
                                        int b, int h0, int j0, int lm, int lq) {
#pragma unroll
  for (int jt = 0; jt < 2; ++jt) {
    const unsigned short* kp =
        &Kb[(((size_t)(b * H_ + h0) * N_) + j0 + jt * 16 + lm) * D_ + lq * 8];
    kr[jt][0] = *(const s16x8*)kp;
    kr[jt][1] = *(const s16x8*)(kp + 32);
  }
}

// single-head Vt fragment load: vt[nd]
__device__ __forceinline__ void load_v1(s16x8 (&vt)[4],
                                        const unsigned short* __restrict__ Vt,
                                        int b, int h0, int j0, int lm, int lq) {
#pragma unroll
  for (int nd = 0; nd < 4; ++nd)
    vt[nd] = *(const s16x8*)&Vt[(((size_t)(b * H_ + h0) * D_) + nd * 16 + lm) * N_ + j0 + lq * 8];
}

// scores: QK^T for 1 head x 32 i x 32 j -> bf16 into Sb (b16 scatter)
__device__ __forceinline__ void scores_phase1(const s16x8 (&aq)[2][2],
                                              const s16x8 (&kr)[2][2],
                                              unsigned short* Sb,
                                              int lm, int lq, int h0) {
#pragma unroll
  for (int jt = 0; jt < 2; ++jt) {
    f32x4 c[2];
    __builtin_amdgcn_s_setprio(1);
#pragma unroll
    for (int mi = 0; mi < 2; ++mi) {
      f32x4 cc = {};
      cc = mfma16(aq[mi][0], kr[jt][0], cc);
      cc = mfma16(aq[mi][1], kr[jt][1], cc);
      c[mi] = cc;
    }
    __builtin_amdgcn_s_setprio(0);
#pragma unroll
    for (int mi = 0; mi < 2; ++mi)
#pragma unroll
      for (int r = 0; r < 4; ++r)
        Sb[(mi * 16 + lq * 4 + r) * SS_I + jt * SLOT + lm * SS_J + h0] = f2bf(c[mi][r]);
  }
}

// -------------------- pass 1: row sums l ----------------------------
__global__ __launch_bounds__(1024, 4) void attn_l(const unsigned short* __restrict__ Qb,
                                                  const unsigned short* __restrict__ Kb,
                                                  const float* __restrict__ wpre,
                                                  const float* __restrict__ bpre,
                                                  float* __restrict__ l_glob) {
  __shared__ unsigned short Ssh[SS_HALF];
  const int tid = threadIdx.x;
  const int wave = tid >> 6, lane = tid & 63;
  const int lm = lane & 15, lq = lane >> 4;
  const int b = blockIdx.z, jh = blockIdx.y;
  const int i0 = blockIdx.x * 32;
  const int j00 = jh * 512;
  const int h0 = wave;  // one head per wave

  // zero-init LDS once (pads must be finite for unguarded reads)
  for (int t = tid; t < SS_HALF; t += 1024) Ssh[t] = 0;

  s16x8 aq[2][2];  // [mi][ks]
#pragma unroll
  for (int mi = 0; mi < 2; ++mi)
#pragma unroll
    for (int ks = 0; ks < 2; ++ks)
      aq[mi][ks] = *(const s16x8*)&Qb[(((size_t)(b * H_ + h0) * N_) + i0 + mi * 16 + lm) * D_ + ks * 32 + lq * 8];

  s16x8 apre;
#pragma unroll
  for (int t = 0; t < 8; ++t) apre[t] = 0;
  if (lq < 2)
#pragma unroll
    for (int t = 0; t < 8; ++t) apre[t] = (short)f2bf(wpre[lm * 16 + lq * 8 + t] * 0.125f);
  float bpreL[4];
#pragma unroll
  for (int r = 0; r < 4; ++r) bpreL[r] = bpre[lq * 4 + r] * LOG2E;

  float lacc[2][4] = {};

  s16x8 kr[2][2];
  load_k1(kr, Kb, b, h0, j00, lm, lq);

  for (int t = 0; t < 16; ++t) {
    bar_lgkm();  // prev premix reads done before score overwrite (+init)
    scores_phase1(aq, kr, Ssh, lm, lq, h0);
    // reload kr for next step: latency hides under premix + barrier
    const int jn = j00 + (t + 1 < 16 ? (t + 1) * 32 : 480);
    load_k1(kr, Kb, b, h0, jn, lm, lq);
    bar_lgkm();  // scores visible
    // batched premix: all reads -> all MFMA -> exp accumulate
#pragma unroll
    for (int jt = 0; jt < 2; ++jt) {
      s16x4 p0[2], p1[2];
#pragma unroll
      for (int u = 0; u < 2; ++u) {
        const unsigned short* srow = &Ssh[(wave * 2 + u) * SS_I + jt * SLOT + lm * SS_J + lq * 8];
        p0[u] = *(const s16x4*)srow;
        p1[u] = *(const s16x4*)(srow + 4);
      }
#pragma unroll
      for (int u = 0; u < 2; ++u) {
        s16x8 bs;
        bs[0] = p0[u][0]; bs[1] = p0[u][1]; bs[2] = p0[u][2]; bs[3] = p0[u][3];
        bs[4] = p1[u][0]; bs[5] = p1[u][1]; bs[6] = p1[u][2]; bs[7] = p1[u][3];
        f32x4 c = {};
        c = mfma16(apre, bs, c);
#pragma unroll
        for (int r = 0; r < 4; ++r)
          lacc[u][r] += exp2_hw(__fmaf_rn(c[r], LOG2E, bpreL[r]));
      }
    }
  }
#pragma unroll
  for (int ig = 0; ig < 2; ++ig)
#pragma unroll
    for (int r = 0; r < 4; ++r) {
      float v = lacc[ig][r];
      v += __shfl_xor(v, 1); v += __shfl_xor(v, 2);
      v += __shfl_xor(v, 4); v += __shfl_xor(v, 8);
      if (lm == 0)
        atomicAdd(&l_glob[((size_t)b * N_ + i0 + wave * 2 + ig) * H_ + lq * 4 + r], v);
    }
}

// -------------------- pass 2: full pipeline + AV --------------------
__global__ __launch_bounds__(1024, 4) void attn_av(const unsigned short* __restrict__ Qb,
                                                   const unsigned short* __restrict__ Kb,
                                                   const unsigned short* __restrict__ Vt,
                                                   const float* __restrict__ wpre,
                                                   const float* __restrict__ bpre,
                                                   const float* __restrict__ wpost,
                                                   const float* __restrict__ bpost,
                                                   const float* __restrict__ l_glob,
                                                   float* __restrict__ Opart) {
  __shared__ unsigned short Ssh[2 * SS_HALF];
  __shared__ unsigned short Psh[2 * PS_HALF];
  __shared__ float linvs[512];
  const int tid = threadIdx.x;
  const int wave = tid >> 6, lane = tid & 63;
  const int lm = lane & 15, lq = lane >> 4;
  const int b = blockIdx.z, jh = blockIdx.y;
  const int i0 = blockIdx.x * 32;
  const int j00 = jh * 512;
  const int h0 = wave;  // one head per wave
  float* Oout = Opart + (size_t)jh * ((size_t)B_ * N_ * 1024);

  // zero-init both S buffers (pads finite) + stage linv
  for (int t = tid; t < 2 * SS_HALF; t += 1024) Ssh[t] = 0;
  if (tid < 512)
    linvs[tid] = 1.0f / l_glob[((size_t)b * N_ + i0 + (tid >> 4)) * H_ + (tid & 15)];

  s16x8 aq[2][2];  // [mi][ks]
#pragma unroll
  for (int mi = 0; mi < 2; ++mi)
#pragma unroll
    for (int ks = 0; ks < 2; ++ks)
      aq[mi][ks] = *(const s16x8*)&Qb[(((size_t)(b * H_ + h0) * N_) + i0 + mi * 16 + lm) * D_ + ks * 32 + lq * 8];

  s16x8 apre, apost;
#pragma unroll
  for (int t = 0; t < 8; ++t) { apre[t] = 0; apost[t] = 0; }
  if (lq < 2)
#pragma unroll
    for (int t = 0; t < 8; ++t) {
      apre[t] = (short)f2bf(wpre[lm * 16 + lq * 8 + t] * 0.125f);
      apost[t] = (short)f2bf(wpost[lm * 16 + lq * 8 + t]);
    }
  float bpre_r[4];
#pragma unroll
  for (int r = 0; r < 4; ++r) bpre_r[r] = bpre[lq * 4 + r];
  const float bpost_lm = bpost[lm];  // postmix output col = g' = lm

  // E-transpose bpermute lane indices (byte addr = lane*4); lq>=2 reads
  // wrap to a finite lane (multiplied by apost=0, don't-care).
  const int bpA = ((((2 * lq) & 3) * 16 + lm) << 2);
  const int bpB = ((((2 * lq + 1) & 3) * 16 + lm) << 2);

  __syncthreads();  // init + linv visible to all waves (full drain, once)

  // log-domain fold: exp(c+bpre)*linv = 2^(fma(c, log2e, bl))
  float bl[2][4];
#pragma unroll
  for (int u = 0; u < 2; ++u)
#pragma unroll
    for (int r = 0; r < 4; ++r)
      bl[u][r] = bpre_r[r] * LOG2E + log2f(linvs[(wave * 2 + u) * 16 + lq * 4 + r]);

  f32x4 acc[2][4] = {};  // [mi][nd]

  // ---- prologue: K/V for step 0, scores[0] -> buf0, K for step 1 ----
  s16x8 kr[2][2];
  load_k1(kr, Kb, b, h0, j00, lm, lq);
  s16x8 vtbuf[2][4];
  load_v1(vtbuf[0], Vt, b, h0, j00, lm, lq);
  scores_phase1(aq, kr, &Ssh[0], lm, lq, h0);
  load_k1(kr, Kb, b, h0, j00 + 32, lm, lq);
  bar_lgkm();  // scores[0] visible

#pragma unroll 2
  for (int t = 0; t < 16; ++t) {
    unsigned short* Sc = &Ssh[(t & 1) * SS_HALF];
    unsigned short* Pc = &Psh[(t & 1) * PS_HALF];
    // ---- 1. hoist ALL S[t] fragment reads (8x ds_read_b64): their
    //      latency hides under the scores MFMA cluster issued next ----
    s16x4 p0[2][2], p1[2][2];  // [jt][u]
#pragma unroll
    for (int jt = 0; jt < 2; ++jt)
#pragma unroll
      for (int u = 0; u < 2; ++u) {
        const unsigned short* srow = &Sc[(wave * 2 + u) * SS_I + jt * SLOT + lm * SS_J + lq * 8];
        p0[jt][u] = *(const s16x4*)srow;
        p1[jt][u] = *(const s16x4*)(srow + 4);
      }
    // ---- 2. scores[t+1] into the other S buffer (kr prefetched) ----
    if (t < 15) {
      scores_phase1(aq, kr, &Ssh[((t + 1) & 1) * SS_HALF], lm, lq, h0);
      const int jn = j00 + (t + 2 < 16 ? (t + 2) * 32 : 480);
      load_k1(kr, Kb, b, h0, jn, lm, lq);
    }
    // ---- 3. premix -> exp2 -> bpermute -> postmix -> P[t] ----
#pragma unroll
    for (int jt = 0; jt < 2; ++jt) {
      f32x4 cpre[2];
#pragma unroll
      for (int u = 0; u < 2; ++u) {
        s16x8 bs;
        bs[0] = p0[jt][u][0]; bs[1] = p0[jt][u][1]; bs[2] = p0[jt][u][2]; bs[3] = p0[jt][u][3];
        bs[4] = p1[jt][u][0]; bs[5] = p1[jt][u][1]; bs[6] = p1[jt][u][2]; bs[7] = p1[jt][u][3];
        f32x4 c = {};
        cpre[u] = mfma16(apre, bs, c);
      }
#pragma unroll
      for (int u = 0; u < 2; ++u) {
        // E = 2^(fma(cpre, log2e, bl)); bpermute into postmix A-layout
        float e0 = exp2_hw(__fmaf_rn(cpre[u][0], LOG2E, bl[u][0]));
        float e1 = exp2_hw(__fmaf_rn(cpre[u][1], LOG2E, bl[u][1]));
        float e2 = exp2_hw(__fmaf_rn(cpre[u][2], LOG2E, bl[u][2]));
        float e3 = exp2_hw(__fmaf_rn(cpre[u][3], LOG2E, bl[u][3]));
        int e01 = (int)((unsigned int)f2bf(e0) | ((unsigned int)f2bf(e1) << 16));
        int e23 = (int)((unsigned int)f2bf(e2) | ((unsigned int)f2bf(e3) << 16));
        union { int i[4]; s16x8 v; } cv;
        cv.i[0] = __builtin_amdgcn_ds_bpermute(bpA, e01);
        cv.i[1] = __builtin_amdgcn_ds_bpermute(bpA, e23);
        cv.i[2] = __builtin_amdgcn_ds_bpermute(bpB, e01);
        cv.i[3] = __builtin_amdgcn_ds_bpermute(bpB, e23);
        f32x4 c2 = {};
        c2 = mfma16(cv.v, apost, c2);
        // c2: row = lq*4+r = j (within jt tile), col = lm = g'
        s16x4 pv;
#pragma unroll
        for (int r = 0; r < 4; ++r) pv[r] = (short)f2bf(c2[r] + bpost_lm);
        *(s16x4*)&Pc[lm * PS_G + (wave * 2 + u) * PS_J + jt * 16 + lq * 4] = pv;  // b64
      }
    }
    bar_lgkm();  // P[t] + scores[t+1] visible; globals stay in flight
    // ---- AV[t]: ap ds_reads first, V[t+1] load issues, then MFMAs ----
    s16x8 ap[2];
#pragma unroll
    for (int mi = 0; mi < 2; ++mi) {
      const unsigned short* pb = &Pc[h0 * PS_G + (mi * 16 + lm) * PS_J + lq * 8];
      s16x4 a0 = *(const s16x4*)pb;
      s16x4 a1 = *(const s16x4*)(pb + 4);
      s16x8 tt;
      tt[0] = a0[0]; tt[1] = a0[1]; tt[2] = a0[2]; tt[3] = a0[3];
      tt[4] = a1[0]; tt[5] = a1[1]; tt[6] = a1[2]; tt[7] = a1[3];
      ap[mi] = tt;
    }
    if (t < 15)
      load_v1(vtbuf[(t + 1) & 1], Vt, b, h0, j00 + (t + 1) * 32, lm, lq);
    __builtin_amdgcn_s_setprio(1);
#pragma unroll
    for (int mi = 0; mi < 2; ++mi)
#pragma unroll
      for (int nd = 0; nd < 4; ++nd)
        acc[mi][nd] = mfma16(ap[mi], vtbuf[t & 1][nd], acc[mi][nd]);
    __builtin_amdgcn_s_setprio(0);
  }
#pragma unroll
  for (int mi = 0; mi < 2; ++mi)
#pragma unroll
    for (int nd = 0; nd < 4; ++nd)
#pragma unroll
      for (int r = 0; r < 4; ++r)
        Oout[((size_t)b * N_ + i0 + mi * 16 + lq * 4 + r) * 1024 + h0 * 64 + nd * 16 + lm] = acc[mi][nd][r];
}

extern "C" void kernel_launch(void* const* d_in, const int* in_sizes, int n_in,
                              void* d_out, int out_size, void* d_ws,
                              size_t ws_size, hipStream_t stream) {
  (void)in_sizes; (void)n_in; (void)out_size; (void)ws_size;
  const float* x      = (const float*)d_in[0];
  const float* w_qkv  = (const float*)d_in[1];
  const float* w_out  = (const float*)d_in[2];
  const float* w_pre  = (const float*)d_in[3];
  const float* b_pre  = (const float*)d_in[4];
  const float* w_post = (const float*)d_in[5];
  const float* b_post = (const float*)d_in[6];

  float* out = (float*)d_out;                        // (B,N,F) fp32
  float* kv  = out + (size_t)B_ * N_ * F_;           // (2,B,H,N,D) fp32

  unsigned short* xb  = (unsigned short*)d_ws;            // 4096x1024
  unsigned short* wqb = xb + (size_t)4096 * 1024;         // 3072x1024 (permuted)
  unsigned short* wob = wqb + (size_t)3072 * 1024;        // 1024x1024
  unsigned short* Qb  = wob + (size_t)1024 * 1024;        // (B,H,N,D)
  unsigned short* Kb  = Qb + (size_t)B_ * H_ * N_ * D_;
  unsigned short* Vt  = Kb + (size_t)B_ * H_ * N_ * D_;   // (B,H,D,N)
  unsigned short* O1  = Vt + (size_t)B_ * H_ * N_ * D_;   // (B,N,1024) bf16
  float* l_glob = (float*)(O1 + (size_t)B_ * N_ * F_);    // (B,N,16) fp32
  float* Oh = l_glob + (size_t)B_ * N_ * H_;              // 4 x (B,N,1024) fp32

  cvt_bf16<<<dim3(4096 * 1024 / 8 / 256), 256, 0, stream>>>(x, xb, 4096 * 1024 / 8);
  cvt_wqkv_perm<<<dim3(3072 * 128 / 256), 256, 0, stream>>>(w_qkv, wqb);
  cvt_bf16<<<dim3(1024 * 1024 / 8 / 256), 256, 0, stream>>>(w_out, wob, 1024 * 1024 / 8);
  hipMemsetAsync(l_glob, 0, (size_t)B_ * N_ * H_ * 4, stream);

  gemm_bf16<0><<<dim3(3072 / 128, 4096 / 128), 256, 0, stream>>>(xb, wqb, kv, Qb, Kb, Vt);

  attn_l<<<dim3(N_ / 32, 4, B_), 1024, 0, stream>>>(Qb, Kb, w_pre, b_pre, l_glob);
  attn_av<<<dim3(N_ / 32, 4, B_), 1024, 0, stream>>>(Qb, Kb, Vt, w_pre, b_pre, w_post, b_post,
                                                     l_glob, Oh);

  cvt_sum4<<<dim3(B_ * N_ * F_ / 4 / 256), 256, 0, stream>>>(Oh, O1);

  gemm_bf16<1><<<dim3(1024 / 128, 4096 / 128), 256, 0, stream>>>(O1, wob, out, nullptr, nullptr, nullptr);
}

// Round 11
// 382.065 us; speedup vs baseline: 10.6082x; 10.6082x over previous
//
#include <hip/hip_runtime.h>
#include <hip/hip_bf16.h>
#include <cstdint>
#include <cstddef>

#define B_ 2
#define N_ 2048
#define F_ 1024
#define H_ 16
#define D_ 64
#define LOG2E 1.44269504f

typedef float f32x4 __attribute__((ext_vector_type(4)));
typedef short s16x8 __attribute__((ext_vector_type(8)));
typedef short s16x4 __attribute__((ext_vector_type(4)));

__device__ __forceinline__ unsigned short f2bf(float f) {
  union { __hip_bfloat16 h; unsigned short u; } c;
  c.h = __float2bfloat16(f);
  return c.u;
}

// hardware 2^x (v_exp_f32 IS base-2). plain exp2f lowers to the precise
// __ocml_exp2_f32 libm path (round-8 lesson: VALUBusy 31.6->38.4).
__device__ __forceinline__ float exp2_hw(float x) {
  float r;
  asm("v_exp_f32 %0, %1" : "=v"(r) : "v"(x));
  return r;
}

// raw barrier: drain LDS ops only; global loads stay in flight (T3/T4).
__device__ __forceinline__ void bar_lgkm() {
  asm volatile("s_waitcnt lgkmcnt(0)" ::: "memory");
  __builtin_amdgcn_s_barrier();
}

// async global->LDS, 16B per lane; LDS dest = uniform base + lane*16.
__device__ __forceinline__ void gload_lds16(const void* g, void* l) {
  __builtin_amdgcn_global_load_lds(
      (const __attribute__((address_space(1))) void*)g,
      (__attribute__((address_space(3))) void*)l, 16, 0, 0);
}

// ---------------------------------------------------------------------
// fp32 -> bf16 bulk convert (8 elems/thread)
// ---------------------------------------------------------------------
__global__ __launch_bounds__(256) void cvt_bf16(const float* __restrict__ in,
                                                unsigned short* __restrict__ out,
                                                int n8) {
  const int t = blockIdx.x * 256 + threadIdx.x;
  if (t >= n8) return;
  const float4* p = (const float4*)in + (size_t)t * 2;
  float4 a = p[0], b = p[1];
  s16x8 o;
  o[0] = f2bf(a.x); o[1] = f2bf(a.y); o[2] = f2bf(a.z); o[3] = f2bf(a.w);
  o[4] = f2bf(b.x); o[5] = f2bf(b.y); o[6] = f2bf(b.z); o[7] = f2bf(b.w);
  *((s16x8*)out + t) = o;
}

// ---------------------------------------------------------------------
// w_qkv fp32 -> bf16 with row permutation: out row colp = c*1024 + h*64 + d
// ---------------------------------------------------------------------
__global__ __launch_bounds__(256) void cvt_wqkv_perm(const float* __restrict__ in,
                                                     unsigned short* __restrict__ out) {
  const int t = blockIdx.x * 256 + threadIdx.x;
  const int rowp = t >> 7;
  const int kk = (t & 127) * 8;
  const int c = rowp >> 10, rem = rowp & 1023;
  const int h = rem >> 6, d = rem & 63;
  const float* p = in + (size_t)(h * 192 + d * 3 + c) * 1024 + kk;
  float4 a = *(const float4*)p, b = *(const float4*)(p + 4);
  s16x8 o;
  o[0] = f2bf(a.x); o[1] = f2bf(a.y); o[2] = f2bf(a.z); o[3] = f2bf(a.w);
  o[4] = f2bf(b.x); o[5] = f2bf(b.y); o[6] = f2bf(b.z); o[7] = f2bf(b.w);
  *((s16x8*)&out[(size_t)rowp * 1024 + kk]) = o;
}

// ---------------------------------------------------------------------
// sum the four j-quarter fp32 O partials -> bf16 O1
// ---------------------------------------------------------------------
__global__ __launch_bounds__(256) void cvt_sum4(const float* __restrict__ a,
                                                unsigned short* __restrict__ out) {
  const int t = blockIdx.x * 256 + threadIdx.x;
  const size_t stride = (size_t)B_ * N_ * 1024 / 4;  // in float4 units
  float4 x0 = *((const float4*)a + t);
  float4 x1 = *((const float4*)a + stride + t);
  float4 x2 = *((const float4*)a + 2 * stride + t);
  float4 x3 = *((const float4*)a + 3 * stride + t);
  s16x4 o;
  o[0] = f2bf((x0.x + x1.x) + (x2.x + x3.x));
  o[1] = f2bf((x0.y + x1.y) + (x2.y + x3.y));
  o[2] = f2bf((x0.z + x1.z) + (x2.z + x3.z));
  o[3] = f2bf((x0.w + x1.w) + (x2.w + x3.w));
  *((s16x4*)out + t) = o;
}

// ---------------------------------------------------------------------
// MFMA GEMM: global_load_lds width=16 staging into a LINEAR [128][64]
// LDS tile + XOR slot-swizzle (both-sides-or-neither, rule #21):
//   - dest is linear (async op writes base+lane*16), so the SOURCE is
//     permuted: lane l (row r = c*8 + l>>3, dest slot l&7) loads global
//     16B-slot (l&7)^(l>>3) of its row.
//   - reads apply the same XOR: slot' = (ks*4+lq) ^ (R&7).
// ---------------------------------------------------------------------
template <int MODE>
__global__ __launch_bounds__(256) void gemm_bf16(const unsigned short* __restrict__ A,
                                                 const unsigned short* __restrict__ W,
                                                 float* __restrict__ o0,
                                                 unsigned short* __restrict__ oQ,
                                                 unsigned short* __restrict__ oK,
                                                 unsigned short* __restrict__ oVt) {
  __shared__ unsigned short As[128 * 64];
  __shared__ unsigned short Bs[128 * 64];
  const int m0 = blockIdx.y * 128, c0 = blockIdx.x * 128;
  const int tid = threadIdx.x;
  const int wave = tid >> 6, lane = tid & 63;
  const int wm = (wave & 1) * 64, wn = (wave >> 1) * 64;
  const int lm = lane & 15, lq = lane >> 4;
  const int srow = lane >> 3;                 // row within 8-row chunk
  const int skq = ((lane & 7) ^ srow) * 8;    // SWIZZLED source slot (shorts)
  const int lm7 = lm & 7;
  f32x4 acc[4][4] = {};
  for (int k0 = 0; k0 < 1024; k0 += 64) {
#pragma unroll
    for (int it = 0; it < 4; ++it) {
      const int c = wave * 4 + it;     // chunk: 8 rows x 64 shorts = 1 KB
      const int row = c * 8 + srow;
      gload_lds16(&A[(size_t)(m0 + row) * 1024 + k0 + skq], &As[c * 512]);
      gload_lds16(&W[(size_t)(c0 + row) * 1024 + k0 + skq], &Bs[c * 512]);
    }
    __syncthreads();  // drains vmcnt (async LDS deposits complete)
#pragma unroll
    for (int ks = 0; ks < 2; ++ks) {
      s16x8 af[4], bfr[4];
#pragma unroll
      for (int i = 0; i < 4; ++i) {
        const int Ra = wm + i * 16 + lm;
        const int Rb = wn + i * 16 + lm;
        af[i] = *(const s16x8*)&As[Ra * 64 + (((ks * 4 + lq) ^ lm7) * 8)];
        bfr[i] = *(const s16x8*)&Bs[Rb * 64 + (((ks * 4 + lq) ^ lm7) * 8)];
      }
#pragma unroll
      for (int i = 0; i < 4; ++i)
#pragma unroll
        for (int j = 0; j < 4; ++j)
          acc[i][j] = __builtin_amdgcn_mfma_f32_16x16x32_bf16(af[i], bfr[j], acc[i][j], 0, 0, 0);
    }
    __syncthreads();
  }
  if (MODE == 1) {
#pragma unroll
    for (int i = 0; i < 4; ++i)
#pragma unroll
      for (int j = 0; j < 4; ++j)
#pragma unroll
        for (int r = 0; r < 4; ++r) {
          const int m = m0 + wm + i * 16 + lq * 4 + r;
          const int col = c0 + wn + j * 16 + lm;
          o0[(size_t)m * 1024 + col] = acc[i][j][r];
        }
  } else {
    const int cls = blockIdx.x >> 3;
    const int colbase = (blockIdx.x & 7) * 128;
    if (cls == 0) {
#pragma unroll
      for (int i = 0; i < 4; ++i)
#pragma unroll
        for (int j = 0; j < 4; ++j) {
          const int cl = colbase + wn + j * 16 + lm;
          const int h = cl >> 6, d = cl & 63;
#pragma unroll
          for (int r = 0; r < 4; ++r) {
            const int m = m0 + wm + i * 16 + lq * 4 + r;
            const int bb = m >> 11, n = m & 2047;
            oQ[(((size_t)bb * H_ + h) * N_ + n) * D_ + d] = f2bf(acc[i][j][r]);
          }
        }
    } else if (cls == 1) {
#pragma unroll
      for (int i = 0; i < 4; ++i)
#pragma unroll
        for (int j = 0; j < 4; ++j) {
          const int cl = colbase + wn + j * 16 + lm;
          const int h = cl >> 6, d = cl & 63;
#pragma unroll
          for (int r = 0; r < 4; ++r) {
            const int m = m0 + wm + i * 16 + lq * 4 + r;
            const int bb = m >> 11, n = m & 2047;
            const size_t idx = (((size_t)bb * H_ + h) * N_ + n) * D_ + d;
            o0[idx] = acc[i][j][r];
            oK[idx] = f2bf(acc[i][j][r]);
          }
        }
    } else {
#pragma unroll
      for (int i = 0; i < 4; ++i) {
        const int n0 = m0 + wm + i * 16 + lq * 4;
        const int bb = n0 >> 11, nl = n0 & 2047;
#pragma unroll
        for (int j = 0; j < 4; ++j) {
          const int cl = colbase + wn + j * 16 + lm;
          const int h = cl >> 6, d = cl & 63;
          s16x4 vp;
#pragma unroll
          for (int r = 0; r < 4; ++r) {
            const size_t idx = (((size_t)bb * H_ + h) * N_ + nl + r) * D_ + d;
            o0[(size_t)B_ * H_ * N_ * D_ + idx] = acc[i][j][r];
            vp[r] = (short)f2bf(acc[i][j][r]);
          }
          *(s16x4*)&oVt[(((size_t)bb * H_ + h) * D_ + d) * N_ + nl] = vp;
        }
      }
    }
  }
}

// =====================================================================
// Fused attention v13 (FINAL, round-9 verified: attn_av 154.5us, no
// spill). Round-10 lesson: 1024-thread blocks hard-cap registers at
// 128 (16 waves must fit 4/SIMD x 128 = 512 pool), so the deeper ILP
// reorder spilled catastrophically (FETCH 70MB->1.3GB). This structure
// is the register-feasible optimum of the explored family:
//   - 16 waves x 1 head, single-barrier software pipeline,
//     double-buffered S/P (158.7 KB LDS), K/V register prefetch,
//     lgkm-only barriers (globals stay in flight across barriers),
//     bpermute E-transpose (no LDS round trip), setprio on MFMA
//     clusters, log-domain softmax fold via HW v_exp_f32.
// =====================================================================
#define SS_J 20
#define SLOT 320
#define SS_I 644                  // 2*SLOT + 4 pad
#define SS_HALF (32 * SS_I + 16)  // one S buffer (+16 tail pad), shorts
#define PS_J 36
#define PS_G 1156                 // 32*36 + 4
#define PS_HALF (16 * PS_G)       // one P buffer, shorts

__device__ __forceinline__ f32x4 mfma16(s16x8 a, s16x8 b, f32x4 c) {
  return __builtin_amdgcn_mfma_f32_16x16x32_bf16(a, b, c, 0, 0, 0);
}

// single-head K fragment load: kr[jt][half]
__device__ __forceinline__ void load_k1(s16x8 (&kr)[2][2],
                                        const unsigned short* __restrict__ Kb,
                                        int b, int h0, int j0, int lm, int lq) {
#pragma unroll
  for (int jt = 0; jt < 2; ++jt) {
    const unsigned short* kp =
        &Kb[(((size_t)(b * H_ + h0) * N_) + j0 + jt * 16 + lm) * D_ + lq * 8];
    kr[jt][0] = *(const s16x8*)kp;
    kr[jt][1] = *(const s16x8*)(kp + 32);
  }
}

// single-head Vt fragment load: vt[nd]
__device__ __forceinline__ void load_v1(s16x8 (&vt)[4],
                                        const unsigned short* __restrict__ Vt,
                                        int b, int h0, int j0, int lm, int lq) {
#pragma unroll
  for (int nd = 0; nd < 4; ++nd)
    vt[nd] = *(const s16x8*)&Vt[(((size_t)(b * H_ + h0) * D_) + nd * 16 + lm) * N_ + j0 + lq * 8];
}

// scores: QK^T for 1 head x 32 i x 32 j -> bf16 into Sb (b16 scatter)
__device__ __forceinline__ void scores_phase1(const s16x8 (&aq)[2][2],
                                              const s16x8 (&kr)[2][2],
                                              unsigned short* Sb,
                                              int lm, int lq, int h0) {
#pragma unroll
  for (int jt = 0; jt < 2; ++jt) {
    f32x4 c[2];
    __builtin_amdgcn_s_setprio(1);
#pragma unroll
    for (int mi = 0; mi < 2; ++mi) {
      f32x4 cc = {};
      cc = mfma16(aq[mi][0], kr[jt][0], cc);
      cc = mfma16(aq[mi][1], kr[jt][1], cc);
      c[mi] = cc;
    }
    __builtin_amdgcn_s_setprio(0);
#pragma unroll
    for (int mi = 0; mi < 2; ++mi)
#pragma unroll
      for (int r = 0; r < 4; ++r)
        Sb[(mi * 16 + lq * 4 + r) * SS_I + jt * SLOT + lm * SS_J + h0] = f2bf(c[mi][r]);
  }
}

// -------------------- pass 1: row sums l ----------------------------
__global__ __launch_bounds__(1024, 4) void attn_l(const unsigned short* __restrict__ Qb,
                                                  const unsigned short* __restrict__ Kb,
                                                  const float* __restrict__ wpre,
                                                  const float* __restrict__ bpre,
                                                  float* __restrict__ l_glob) {
  __shared__ unsigned short Ssh[SS_HALF];
  const int tid = threadIdx.x;
  const int wave = tid >> 6, lane = tid & 63;
  const int lm = lane & 15, lq = lane >> 4;
  const int b = blockIdx.z, jh = blockIdx.y;
  const int i0 = blockIdx.x * 32;
  const int j00 = jh * 512;
  const int h0 = wave;  // one head per wave

  // zero-init LDS once (pads must be finite for unguarded reads)
  for (int t = tid; t < SS_HALF; t += 1024) Ssh[t] = 0;

  s16x8 aq[2][2];  // [mi][ks]
#pragma unroll
  for (int mi = 0; mi < 2; ++mi)
#pragma unroll
    for (int ks = 0; ks < 2; ++ks)
      aq[mi][ks] = *(const s16x8*)&Qb[(((size_t)(b * H_ + h0) * N_) + i0 + mi * 16 + lm) * D_ + ks * 32 + lq * 8];

  s16x8 apre;
#pragma unroll
  for (int t = 0; t < 8; ++t) apre[t] = 0;
  if (lq < 2)
#pragma unroll
    for (int t = 0; t < 8; ++t) apre[t] = (short)f2bf(wpre[lm * 16 + lq * 8 + t] * 0.125f);
  float bpreL[4];
#pragma unroll
  for (int r = 0; r < 4; ++r) bpreL[r] = bpre[lq * 4 + r] * LOG2E;

  float lacc[2][4] = {};

  s16x8 kr[2][2];
  load_k1(kr, Kb, b, h0, j00, lm, lq);

  for (int t = 0; t < 16; ++t) {
    bar_lgkm();  // prev premix reads done before score overwrite (+init)
    scores_phase1(aq, kr, Ssh, lm, lq, h0);
    // reload kr for next step: latency hides under premix + barrier
    const int jn = j00 + (t + 1 < 16 ? (t + 1) * 32 : 480);
    load_k1(kr, Kb, b, h0, jn, lm, lq);
    bar_lgkm();  // scores visible
    // batched premix: all reads -> all MFMA -> exp accumulate
#pragma unroll
    for (int jt = 0; jt < 2; ++jt) {
      s16x4 p0[2], p1[2];
#pragma unroll
      for (int u = 0; u < 2; ++u) {
        const unsigned short* srow = &Ssh[(wave * 2 + u) * SS_I + jt * SLOT + lm * SS_J + lq * 8];
        p0[u] = *(const s16x4*)srow;
        p1[u] = *(const s16x4*)(srow + 4);
      }
#pragma unroll
      for (int u = 0; u < 2; ++u) {
        s16x8 bs;
        bs[0] = p0[u][0]; bs[1] = p0[u][1]; bs[2] = p0[u][2]; bs[3] = p0[u][3];
        bs[4] = p1[u][0]; bs[5] = p1[u][1]; bs[6] = p1[u][2]; bs[7] = p1[u][3];
        f32x4 c = {};
        c = mfma16(apre, bs, c);
#pragma unroll
        for (int r = 0; r < 4; ++r)
          lacc[u][r] += exp2_hw(__fmaf_rn(c[r], LOG2E, bpreL[r]));
      }
    }
  }
#pragma unroll
  for (int ig = 0; ig < 2; ++ig)
#pragma unroll
    for (int r = 0; r < 4; ++r) {
      float v = lacc[ig][r];
      v += __shfl_xor(v, 1); v += __shfl_xor(v, 2);
      v += __shfl_xor(v, 4); v += __shfl_xor(v, 8);
      if (lm == 0)
        atomicAdd(&l_glob[((size_t)b * N_ + i0 + wave * 2 + ig) * H_ + lq * 4 + r], v);
    }
}

// -------------------- pass 2: full pipeline + AV --------------------
__global__ __launch_bounds__(1024, 4) void attn_av(const unsigned short* __restrict__ Qb,
                                                   const unsigned short* __restrict__ Kb,
                                                   const unsigned short* __restrict__ Vt,
                                                   const float* __restrict__ wpre,
                                                   const float* __restrict__ bpre,
                                                   const float* __restrict__ wpost,
                                                   const float* __restrict__ bpost,
                                                   const float* __restrict__ l_glob,
                                                   float* __restrict__ Opart) {
  __shared__ unsigned short Ssh[2 * SS_HALF];
  __shared__ unsigned short Psh[2 * PS_HALF];
  __shared__ float linvs[512];
  const int tid = threadIdx.x;
  const int wave = tid >> 6, lane = tid & 63;
  const int lm = lane & 15, lq = lane >> 4;
  const int b = blockIdx.z, jh = blockIdx.y;
  const int i0 = blockIdx.x * 32;
  const int j00 = jh * 512;
  const int h0 = wave;  // one head per wave
  float* Oout = Opart + (size_t)jh * ((size_t)B_ * N_ * 1024);

  // zero-init both S buffers (pads finite) + stage linv
  for (int t = tid; t < 2 * SS_HALF; t += 1024) Ssh[t] = 0;
  if (tid < 512)
    linvs[tid] = 1.0f / l_glob[((size_t)b * N_ + i0 + (tid >> 4)) * H_ + (tid & 15)];

  s16x8 aq[2][2];  // [mi][ks]
#pragma unroll
  for (int mi = 0; mi < 2; ++mi)
#pragma unroll
    for (int ks = 0; ks < 2; ++ks)
      aq[mi][ks] = *(const s16x8*)&Qb[(((size_t)(b * H_ + h0) * N_) + i0 + mi * 16 + lm) * D_ + ks * 32 + lq * 8];

  s16x8 apre, apost;
#pragma unroll
  for (int t = 0; t < 8; ++t) { apre[t] = 0; apost[t] = 0; }
  if (lq < 2)
#pragma unroll
    for (int t = 0; t < 8; ++t) {
      apre[t] = (short)f2bf(wpre[lm * 16 + lq * 8 + t] * 0.125f);
      apost[t] = (short)f2bf(wpost[lm * 16 + lq * 8 + t]);
    }
  float bpre_r[4];
#pragma unroll
  for (int r = 0; r < 4; ++r) bpre_r[r] = bpre[lq * 4 + r];
  const float bpost_lm = bpost[lm];  // postmix output col = g' = lm

  // E-transpose bpermute lane indices (byte addr = lane*4); lq>=2 reads
  // wrap to a finite lane (multiplied by apost=0, don't-care).
  const int bpA = ((((2 * lq) & 3) * 16 + lm) << 2);
  const int bpB = ((((2 * lq + 1) & 3) * 16 + lm) << 2);

  __syncthreads();  // init + linv visible to all waves (full drain, once)

  // log-domain fold: exp(c+bpre)*linv = 2^(fma(c, log2e, bl))
  float bl[2][4];
#pragma unroll
  for (int u = 0; u < 2; ++u)
#pragma unroll
    for (int r = 0; r < 4; ++r)
      bl[u][r] = bpre_r[r] * LOG2E + log2f(linvs[(wave * 2 + u) * 16 + lq * 4 + r]);

  f32x4 acc[2][4] = {};  // [mi][nd]

  // ---- prologue: K/V for step 0, scores[0] -> buf0, K for step 1 ----
  s16x8 kr[2][2];
  load_k1(kr, Kb, b, h0, j00, lm, lq);
  s16x8 vt[4];
  load_v1(vt, Vt, b, h0, j00, lm, lq);
  scores_phase1(aq, kr, &Ssh[0], lm, lq, h0);
  load_k1(kr, Kb, b, h0, j00 + 32, lm, lq);
  bar_lgkm();  // scores[0] visible

#pragma unroll 2
  for (int t = 0; t < 16; ++t) {
    unsigned short* Sc = &Ssh[(t & 1) * SS_HALF];
    unsigned short* Pc = &Psh[(t & 1) * PS_HALF];
    // ---- phaseB[t]: S[t] -> premix -> exp2 -> bpermute-transpose ->
    //      postmix -> P[t] ----
#pragma unroll
    for (int jt = 0; jt < 2; ++jt) {
      s16x4 p0[2], p1[2];
#pragma unroll
      for (int u = 0; u < 2; ++u) {
        const unsigned short* srow = &Sc[(wave * 2 + u) * SS_I + jt * SLOT + lm * SS_J + lq * 8];
        p0[u] = *(const s16x4*)srow;
        p1[u] = *(const s16x4*)(srow + 4);
      }
      f32x4 cpre[2];
#pragma unroll
      for (int u = 0; u < 2; ++u) {
        s16x8 bs;
        bs[0] = p0[u][0]; bs[1] = p0[u][1]; bs[2] = p0[u][2]; bs[3] = p0[u][3];
        bs[4] = p1[u][0]; bs[5] = p1[u][1]; bs[6] = p1[u][2]; bs[7] = p1[u][3];
        f32x4 c = {};
        cpre[u] = mfma16(apre, bs, c);
      }
#pragma unroll
      for (int u = 0; u < 2; ++u) {
        // E = 2^(fma(cpre, log2e, bl)); bpermute into postmix A-layout
        float e0 = exp2_hw(__fmaf_rn(cpre[u][0], LOG2E, bl[u][0]));
        float e1 = exp2_hw(__fmaf_rn(cpre[u][1], LOG2E, bl[u][1]));
        float e2 = exp2_hw(__fmaf_rn(cpre[u][2], LOG2E, bl[u][2]));
        float e3 = exp2_hw(__fmaf_rn(cpre[u][3], LOG2E, bl[u][3]));
        int e01 = (int)((unsigned int)f2bf(e0) | ((unsigned int)f2bf(e1) << 16));
        int e23 = (int)((unsigned int)f2bf(e2) | ((unsigned int)f2bf(e3) << 16));
        union { int i[4]; s16x8 v; } cv;
        cv.i[0] = __builtin_amdgcn_ds_bpermute(bpA, e01);
        cv.i[1] = __builtin_amdgcn_ds_bpermute(bpA, e23);
        cv.i[2] = __builtin_amdgcn_ds_bpermute(bpB, e01);
        cv.i[3] = __builtin_amdgcn_ds_bpermute(bpB, e23);
        f32x4 c2 = {};
        c2 = mfma16(cv.v, apost, c2);
        // c2: row = lq*4+r = j (within jt tile), col = lm = g'
        s16x4 pv;
#pragma unroll
        for (int r = 0; r < 4; ++r) pv[r] = (short)f2bf(c2[r] + bpost_lm);
        *(s16x4*)&Pc[lm * PS_G + (wave * 2 + u) * PS_J + jt * 16 + lq * 4] = pv;  // b64
      }
    }
    // ---- scores[t+1] into the other S buffer (kr prefetched) ----
    if (t < 15) {
      scores_phase1(aq, kr, &Ssh[((t + 1) & 1) * SS_HALF], lm, lq, h0);
      const int jn = j00 + (t + 2 < 16 ? (t + 2) * 32 : 480);
      load_k1(kr, Kb, b, h0, jn, lm, lq);
    }
    bar_lgkm();  // P[t] + scores[t+1] visible; globals stay in flight
    // ---- AV[t]: A = P[t], B = vt (prefetched) ----
    s16x8 ap[2];
#pragma unroll
    for (int mi = 0; mi < 2; ++mi) {
      const unsigned short* pb = &Pc[h0 * PS_G + (mi * 16 + lm) * PS_J + lq * 8];
      s16x4 a0 = *(const s16x4*)pb;
      s16x4 a1 = *(const s16x4*)(pb + 4);
      s16x8 tt;
      tt[0] = a0[0]; tt[1] = a0[1]; tt[2] = a0[2]; tt[3] = a0[3];
      tt[4] = a1[0]; tt[5] = a1[1]; tt[6] = a1[2]; tt[7] = a1[3];
      ap[mi] = tt;
    }
    __builtin_amdgcn_s_setprio(1);
#pragma unroll
    for (int mi = 0; mi < 2; ++mi)
#pragma unroll
      for (int nd = 0; nd < 4; ++nd)
        acc[mi][nd] = mfma16(ap[mi], vt[nd], acc[mi][nd]);
    __builtin_amdgcn_s_setprio(0);
    // reload vt for next step: consumed one region later
    const int jv = j00 + (t + 1 < 16 ? (t + 1) * 32 : 480);
    load_v1(vt, Vt, b, h0, jv, lm, lq);
  }
#pragma unroll
  for (int mi = 0; mi < 2; ++mi)
#pragma unroll
    for (int nd = 0; nd < 4; ++nd)
#pragma unroll
      for (int r = 0; r < 4; ++r)
        Oout[((size_t)b * N_ + i0 + mi * 16 + lq * 4 + r) * 1024 + h0 * 64 + nd * 16 + lm] = acc[mi][nd][r];
}

extern "C" void kernel_launch(void* const* d_in, const int* in_sizes, int n_in,
                              void* d_out, int out_size, void* d_ws,
                              size_t ws_size, hipStream_t stream) {
  (void)in_sizes; (void)n_in; (void)out_size; (void)ws_size;
  const float* x      = (const float*)d_in[0];
  const float* w_qkv  = (const float*)d_in[1];
  const float* w_out  = (const float*)d_in[2];
  const float* w_pre  = (const float*)d_in[3];
  const float* b_pre  = (const float*)d_in[4];
  const float* w_post = (const float*)d_in[5];
  const float* b_post = (const float*)d_in[6];

  float* out = (float*)d_out;                        // (B,N,F) fp32
  float* kv  = out + (size_t)B_ * N_ * F_;           // (2,B,H,N,D) fp32

  unsigned short* xb  = (unsigned short*)d_ws;            // 4096x1024
  unsigned short* wqb = xb + (size_t)4096 * 1024;         // 3072x1024 (permuted)
  unsigned short* wob = wqb + (size_t)3072 * 1024;        // 1024x1024
  unsigned short* Qb  = wob + (size_t)1024 * 1024;        // (B,H,N,D)
  unsigned short* Kb  = Qb + (size_t)B_ * H_ * N_ * D_;
  unsigned short* Vt  = Kb + (size_t)B_ * H_ * N_ * D_;   // (B,H,D,N)
  unsigned short* O1  = Vt + (size_t)B_ * H_ * N_ * D_;   // (B,N,1024) bf16
  float* l_glob = (float*)(O1 + (size_t)B_ * N_ * F_);    // (B,N,16) fp32
  float* Oh = l_glob + (size_t)B_ * N_ * H_;              // 4 x (B,N,1024) fp32

  cvt_bf16<<<dim3(4096 * 1024 / 8 / 256), 256, 0, stream>>>(x, xb, 4096 * 1024 / 8);
  cvt_wqkv_perm<<<dim3(3072 * 128 / 256), 256, 0, stream>>>(w_qkv, wqb);
  cvt_bf16<<<dim3(1024 * 1024 / 8 / 256), 256, 0, stream>>>(w_out, wob, 1024 * 1024 / 8);
  hipMemsetAsync(l_glob, 0, (size_t)B_ * N_ * H_ * 4, stream);

  gemm_bf16<0><<<dim3(3072 / 128, 4096 / 128), 256, 0, stream>>>(xb, wqb, kv, Qb, Kb, Vt);

  attn_l<<<dim3(N_ / 32, 4, B_), 1024, 0, stream>>>(Qb, Kb, w_pre, b_pre, l_glob);
  attn_av<<<dim3(N_ / 32, 4, B_), 1024, 0, stream>>>(Qb, Kb, Vt, w_pre, b_pre, w_post, b_post,
                                                     l_glob, Oh);

  cvt_sum4<<<dim3(B_ * N_ * F_ / 4 / 256), 256, 0, stream>>>(Oh, O1);

  gemm_bf16<1><<<dim3(1024 / 128, 4096 / 128), 256, 0, stream>>>(O1, wob, out, nullptr, nullptr, nullptr);
}